// Round 2
// baseline (50115.561 us; speedup 1.0000x reference)
//
#include <hip/hip_runtime.h>
#include <hip/hip_bf16.h>

#define HN 256
#define DN 128
#define SL 1024
#define BN 128
#define NUNF 6

static __device__ __forceinline__ float fexp2(float x) { return __builtin_amdgcn_exp2f(x); }
static __device__ __forceinline__ float frcp(float x) { return __builtin_amdgcn_rcpf(x); }

// Precompute packed parameters into workspace:
//   rp[(i*HN+h)*3]  = { A = -sigma*log2e, Bc = sigma*mu*log2e, Ws = softplus(w)*erev }
//   spp[(d*HN+h)*3] = { SA = -ssig*log2e*iw[d], SBc = ssig*(smu - ib[d])*log2e, SWs = softplus(sw)*serev }
//   hv[0..255]=gleak_p*vleak, hv[256..511]=cm_t, hv[512..767]=cm_t+gleak_p
__global__ void ltc_prep(const float* __restrict__ gleak, const float* __restrict__ vleak,
                         const float* __restrict__ cm,    const float* __restrict__ w,
                         const float* __restrict__ sigma, const float* __restrict__ mu,
                         const float* __restrict__ erev,
                         const float* __restrict__ sw,    const float* __restrict__ ssig,
                         const float* __restrict__ smu,   const float* __restrict__ serev,
                         const float* __restrict__ iw,    const float* __restrict__ ib,
                         float* __restrict__ ws)
{
    const float L2E = 1.44269504088896340736f;
    float* rp  = ws;
    float* spp = ws + 3 * HN * HN;
    float* hv  = ws + 3 * HN * HN + 3 * DN * HN;
    const int stride = gridDim.x * blockDim.x;
    const int tid0 = blockIdx.x * blockDim.x + threadIdx.x;

    for (int idx = tid0; idx < HN * HN; idx += stride) {
        float sg = sigma[idx];
        float wp = log1pf(expf(w[idx]));        // softplus
        rp[3 * idx + 0] = -sg * L2E;
        rp[3 * idx + 1] = sg * mu[idx] * L2E;
        rp[3 * idx + 2] = wp * erev[idx];       // erev is exactly +/-1
    }
    for (int idx = tid0; idx < DN * HN; idx += stride) {
        int d = idx >> 8;                       // / HN
        float sg = ssig[idx];
        float wp = log1pf(expf(sw[idx]));
        spp[3 * idx + 0] = -sg * L2E * iw[d];
        spp[3 * idx + 1] = sg * (smu[idx] - ib[d]) * L2E;
        spp[3 * idx + 2] = wp * serev[idx];
    }
    if (tid0 < HN) {
        float gl = log1pf(expf(gleak[tid0]));
        float ct = log1pf(expf(cm[tid0])) * (float)NUNF;
        hv[tid0]          = gl * vleak[tid0];
        hv[HN + tid0]     = ct;
        hv[2 * HN + tid0] = ct + gl;
    }
}

// One block per batch element. 1024 threads: h = tid&255 (output column),
// c = tid>>8 (reduction chunk: 4 chunks over i or d). Streams packed params
// from L2 each unfold. sigmoid(z) computed as 1/(1 + 2^(A*v+Bc)).
__global__ __launch_bounds__(1024) void ltc_main(
    const float* __restrict__ x, const float* __restrict__ rp,
    const float* __restrict__ spp, const float* __restrict__ hv,
    float* __restrict__ out)
{
    const int b = blockIdx.x;
    const int tid = threadIdx.x;
    const int h = tid & (HN - 1);
    const int c = tid >> 8;

    __shared__ __align__(16) float v_[HN];
    __shared__ __align__(16) float xs[DN];
    __shared__ __align__(16) float sred[4][HN][2];

    float cmt = 0.f, gv = 0.f, dcn = 0.f;
    if (tid < HN) {
        gv  = hv[tid];
        cmt = hv[HN + tid];
        dcn = hv[2 * HN + tid];
        v_[tid] = 0.f;
    }
    __syncthreads();

    const float* xrow = x + (size_t)b * SL * DN;
    float* orow = out + (size_t)b * SL * HN;
    float wns = 0.f, wds = 0.f, vnew = 0.f;

    for (int t = 0; t < SL; ++t) {
        if (tid < DN) xs[tid] = xrow[(size_t)t * DN + tid];
        __syncthreads();

        // ---- sensory stage: reduce over d (32 per chunk) ----
        {
            float sn = 0.f, sd = 0.f;
            const float* p = spp + (size_t)(c * 32 * HN + h) * 3;
            const float4* xv4 = reinterpret_cast<const float4*>(&xs[c * 32]);
            #pragma unroll 2
            for (int j = 0; j < 8; ++j) {
                float4 xv = xv4[j];
                #pragma unroll
                for (int q = 0; q < 4; ++q) {
                    float xq = (q == 0) ? xv.x : (q == 1) ? xv.y : (q == 2) ? xv.z : xv.w;
                    float pa = p[0], pb = p[1], pc = p[2];
                    float u = fexp2(fmaf(pa, xq, pb));
                    float r = frcp(1.0f + u);
                    sn = fmaf(pc, r, sn);
                    sd = fmaf(fabsf(pc), r, sd);
                    p += 3 * HN;
                }
            }
            sred[c][h][0] = sn;
            sred[c][h][1] = sd;
        }
        __syncthreads();
        if (tid < HN) {
            wns = sred[0][tid][0] + sred[1][tid][0] + sred[2][tid][0] + sred[3][tid][0];
            wds = sred[0][tid][1] + sred[1][tid][1] + sred[2][tid][1] + sred[3][tid][1];
        }
        __syncthreads();

        // ---- 6 ODE unfolds: reduce over i (64 per chunk) ----
        #pragma unroll 1
        for (int k = 0; k < NUNF; ++k) {
            float nm = 0.f, dn = 0.f;
            const float* p = rp + (size_t)(c * 64 * HN + h) * 3;
            const float4* v4 = reinterpret_cast<const float4*>(&v_[c * 64]);
            #pragma unroll 2
            for (int j = 0; j < 16; ++j) {
                float4 vv = v4[j];
                #pragma unroll
                for (int q = 0; q < 4; ++q) {
                    float vq = (q == 0) ? vv.x : (q == 1) ? vv.y : (q == 2) ? vv.z : vv.w;
                    float pa = p[0], pb = p[1], pc = p[2];
                    float u = fexp2(fmaf(pa, vq, pb));
                    float r = frcp(1.0f + u);
                    nm = fmaf(pc, r, nm);
                    dn = fmaf(fabsf(pc), r, dn);
                    p += 3 * HN;
                }
            }
            sred[c][h][0] = nm;
            sred[c][h][1] = dn;
            __syncthreads();
            if (tid < HN) {
                float num = sred[0][tid][0] + sred[1][tid][0] + sred[2][tid][0] + sred[3][tid][0] + wns;
                float den = sred[0][tid][1] + sred[1][tid][1] + sred[2][tid][1] + sred[3][tid][1] + wds;
                float vo = v_[tid];
                num = fmaf(cmt, vo, gv) + num;
                den = dcn + den + 1e-8f;
                vnew = num / den;
                v_[tid] = vnew;
            }
            __syncthreads();
        }

        if (tid < HN) orow[(size_t)t * HN + tid] = vnew;
    }
    if (tid < HN) out[(size_t)BN * SL * HN + (size_t)b * HN + tid] = vnew;
}

extern "C" void kernel_launch(void* const* d_in, const int* in_sizes, int n_in,
                              void* d_out, int out_size, void* d_ws, size_t ws_size,
                              hipStream_t stream) {
    const float* x     = (const float*)d_in[0];
    const float* gleak = (const float*)d_in[1];
    const float* vleak = (const float*)d_in[2];
    const float* cm    = (const float*)d_in[3];
    const float* w     = (const float*)d_in[4];
    const float* sigma = (const float*)d_in[5];
    const float* mu    = (const float*)d_in[6];
    const float* erev  = (const float*)d_in[7];
    const float* sw    = (const float*)d_in[8];
    const float* ssig  = (const float*)d_in[9];
    const float* smu   = (const float*)d_in[10];
    const float* serev = (const float*)d_in[11];
    const float* iw    = (const float*)d_in[12];
    const float* ib    = (const float*)d_in[13];

    float* ws = (float*)d_ws;

    ltc_prep<<<128, 256, 0, stream>>>(gleak, vleak, cm, w, sigma, mu, erev,
                                      sw, ssig, smu, serev, iw, ib, ws);

    const float* rp  = ws;
    const float* spp = ws + 3 * HN * HN;
    const float* hv  = ws + 3 * HN * HN + 3 * DN * HN;
    ltc_main<<<BN, 1024, 0, stream>>>(x, rp, spp, hv, (float*)d_out);
}